// Round 5
// baseline (612.040 us; speedup 1.0000x reference)
//
#include <hip/hip_runtime.h>
#include <math.h>

#define HDIM 128

// ---------------- degree histogram (int) ----------------
__global__ __launch_bounds__(256) void deg_hist_k(const int* __restrict__ col,
                                                  int* __restrict__ deg, int E) {
    int e = blockIdx.x * 256 + threadIdx.x;
    if (e < E) atomicAdd(&deg[col[e]], 1);
}

// ---------------- scan1 + degree finish (fused) ----------------
__global__ __launch_bounds__(256) void scan1_k(const int* __restrict__ deg,
                                               int* __restrict__ incl,
                                               int* __restrict__ partial,
                                               float* __restrict__ dis,
                                               float* __restrict__ dinv, int N) {
    int i = blockIdx.x * 256 + threadIdx.x;
    int lane = threadIdx.x & 63;
    int wid = threadIdx.x >> 6;
    int d0 = (i < N) ? deg[i] : 0;
    if (i < N) {
        double d = (double)d0 + 1.0;               // +1 self loop
        dis[i]  = (float)(1.0 / sqrt(d));          // D^-1/2
        dinv[i] = (float)(1.0 / d);                // self-loop norm 1/deg
    }
    int s = d0;
#pragma unroll
    for (int off = 1; off < 64; off <<= 1) {
        int t = __shfl_up(s, off);
        if (lane >= off) s += t;
    }
    __shared__ int wsum[4];
    if (lane == 63) wsum[wid] = s;
    __syncthreads();
    if (threadIdx.x == 0) {
        int run = 0;
#pragma unroll
        for (int w = 0; w < 4; ++w) { int t = wsum[w]; wsum[w] = run; run += t; }
    }
    __syncthreads();
    s += wsum[wid];
    if (i < N) incl[i] = s;
    if (threadIdx.x == 255) partial[blockIdx.x] = s;
}

__global__ __launch_bounds__(512) void scan2_k(int* __restrict__ partial, int NB) {
    __shared__ int sm[512];
    int t = threadIdx.x;
    sm[t] = (t < NB) ? partial[t] : 0;
    __syncthreads();
    for (int off = 1; off < 512; off <<= 1) {
        int v = (t >= off) ? sm[t - off] : 0;
        __syncthreads();
        sm[t] += v;
        __syncthreads();
    }
    if (t < NB) partial[t] = (t == 0) ? 0 : sm[t - 1];
}

__global__ __launch_bounds__(256) void scan3_k(const int* __restrict__ deg,
                                               const int* __restrict__ incl,
                                               const int* __restrict__ partial,
                                               int* __restrict__ row_ptr, int N) {
    int i = blockIdx.x * 256 + threadIdx.x;
    if (i < N) {
        int off = partial[blockIdx.x];
        row_ptr[i] = incl[i] - deg[i] + off;
        if (i == N - 1) row_ptr[N] = incl[i] + off;
    }
}

// ---------------- CSR fill (counting sort by destination) ----------------
__global__ __launch_bounds__(256) void csr_fill_k(const int* __restrict__ row,
                                                  const int* __restrict__ col,
                                                  const float* __restrict__ dis,
                                                  const int* __restrict__ row_ptr,
                                                  int* __restrict__ cursor,
                                                  int2* __restrict__ csr, int E) {
    int e = blockIdx.x * 256 + threadIdx.x;
    if (e >= E) return;
    int r = row[e], c = col[e];
    int pos = atomicAdd(&cursor[c], 1);
    float nrm = dis[r] * dis[c];
    csr[row_ptr[c] + pos] = make_int2(r, __float_as_int(nrm));
}

// ---------------- GEMM: out = relu?(X) @ W [+ bias] ----------------
template<int K, bool RELU, bool BIAS>
__global__ __launch_bounds__(256) void gemm_gcn(const float* __restrict__ X,
                                                const float* __restrict__ W,
                                                const float* __restrict__ b,
                                                float* __restrict__ out, int N) {
    __shared__ float xs[32][68];
    __shared__ float ws[32][HDIM];
    const int tid = threadIdx.x;
    const int tx = tid & 31;
    const int ty = tid >> 5;
    const int n0 = blockIdx.x * 64;

    float acc[8][4];
#pragma unroll
    for (int r = 0; r < 8; ++r)
#pragma unroll
        for (int c = 0; c < 4; ++c) acc[r][c] = 0.f;

    for (int kc = 0; kc < K; kc += 32) {
#pragma unroll
        for (int i = 0; i < 2; ++i) {
            int f = tid + i * 256;
            int r = f >> 3;
            int kq = f & 7;
            float4 v = make_float4(0.f, 0.f, 0.f, 0.f);
            int n = n0 + r;
            if (n < N) v = *reinterpret_cast<const float4*>(X + (size_t)n * K + kc + kq * 4);
            if (RELU) {
                v.x = fmaxf(v.x, 0.f); v.y = fmaxf(v.y, 0.f);
                v.z = fmaxf(v.z, 0.f); v.w = fmaxf(v.w, 0.f);
            }
            xs[kq * 4 + 0][r] = v.x; xs[kq * 4 + 1][r] = v.y;
            xs[kq * 4 + 2][r] = v.z; xs[kq * 4 + 3][r] = v.w;
        }
#pragma unroll
        for (int i = 0; i < 4; ++i) {
            int f = tid + i * 256;
            int kr = f >> 5;
            int c4 = f & 31;
            *reinterpret_cast<float4*>(&ws[kr][c4 * 4]) =
                *reinterpret_cast<const float4*>(W + (size_t)(kc + kr) * HDIM + c4 * 4);
        }
        __syncthreads();
#pragma unroll
        for (int k = 0; k < 32; ++k) {
            float4 xa = *reinterpret_cast<const float4*>(&xs[k][ty * 8]);
            float4 xb = *reinterpret_cast<const float4*>(&xs[k][ty * 8 + 4]);
            float4 w  = *reinterpret_cast<const float4*>(&ws[k][tx * 4]);
            const float xr[8] = {xa.x, xa.y, xa.z, xa.w, xb.x, xb.y, xb.z, xb.w};
            const float wc[4] = {w.x, w.y, w.z, w.w};
#pragma unroll
            for (int r = 0; r < 8; ++r)
#pragma unroll
                for (int c = 0; c < 4; ++c) acc[r][c] += xr[r] * wc[c];
        }
        __syncthreads();
    }
    float4 bb = make_float4(0.f, 0.f, 0.f, 0.f);
    if (BIAS) bb = *reinterpret_cast<const float4*>(b + tx * 4);
#pragma unroll
    for (int r = 0; r < 8; ++r) {
        int n = n0 + ty * 8 + r;
        if (n >= N) continue;
        *reinterpret_cast<float4*>(out + (size_t)n * HDIM + tx * 4) =
            make_float4(acc[r][0] + bb.x, acc[r][1] + bb.y,
                        acc[r][2] + bb.z, acc[r][3] + bb.w);
    }
}

// ---------------- 32-dim input gather: one wave per node ----------------
// lanes 0-31 process even edges, 32-63 odd edges; lane owns feature f = lane&31.
__global__ __launch_bounds__(256) void gather_x_k(const int* __restrict__ row_ptr,
                                                  const int2* __restrict__ csr,
                                                  const float* __restrict__ dinv,
                                                  const float* __restrict__ X,
                                                  float* __restrict__ Y, int N) {
    int c = (blockIdx.x * 256 + threadIdx.x) >> 6;   // node = global wave id
    if (c >= N) return;
    int lane = threadIdx.x & 63;
    int half = lane >> 5;
    int f = lane & 31;
    int j0 = row_ptr[c], j1 = row_ptr[c + 1];
    float acc = 0.f;
    int j = j0 + half;
    for (; j + 2 < j1; j += 4) {
        int2 e0 = csr[j], e1 = csr[j + 2];
        float v0 = X[(size_t)e0.x * 32 + f];
        float v1 = X[(size_t)e1.x * 32 + f];
        acc += __int_as_float(e0.y) * v0 + __int_as_float(e1.y) * v1;
    }
    for (; j < j1; j += 2) {
        int2 en = csr[j];
        acc += __int_as_float(en.y) * X[(size_t)en.x * 32 + f];
    }
    acc += __shfl_xor(acc, 32);
    if (half == 0) {
        float xc = X[(size_t)c * 32 + f];
        Y[(size_t)c * 32 + f] = dinv[c] * xc + acc;
    }
}

// ---------------- 128-dim gather: one wave per node ----------------
// lanes 0-31 process even edges, 32-63 odd edges; lane owns h-quad hq = lane&31.
__global__ __launch_bounds__(256) void gather_k(const int* __restrict__ row_ptr,
                                                const int2* __restrict__ csr,
                                                const float* __restrict__ dinv,
                                                const float* __restrict__ b,
                                                const float* __restrict__ xw,
                                                float* __restrict__ out, int N) {
    int c = (blockIdx.x * 256 + threadIdx.x) >> 6;   // node = global wave id
    if (c >= N) return;
    int lane = threadIdx.x & 63;
    int half = lane >> 5;
    int hq = lane & 31;
    int j0 = row_ptr[c], j1 = row_ptr[c + 1];
    float4 acc = make_float4(0.f, 0.f, 0.f, 0.f);
    int j = j0 + half;
    for (; j + 2 < j1; j += 4) {
        int2 e0 = csr[j], e1 = csr[j + 2];
        float4 v0 = *reinterpret_cast<const float4*>(xw + (size_t)e0.x * HDIM + hq * 4);
        float4 v1 = *reinterpret_cast<const float4*>(xw + (size_t)e1.x * HDIM + hq * 4);
        float n0 = __int_as_float(e0.y), n1 = __int_as_float(e1.y);
        acc.x += n0 * v0.x + n1 * v1.x;
        acc.y += n0 * v0.y + n1 * v1.y;
        acc.z += n0 * v0.z + n1 * v1.z;
        acc.w += n0 * v0.w + n1 * v1.w;
    }
    for (; j < j1; j += 2) {
        int2 en = csr[j];
        float nrm = __int_as_float(en.y);
        float4 v = *reinterpret_cast<const float4*>(xw + (size_t)en.x * HDIM + hq * 4);
        acc.x += nrm * v.x; acc.y += nrm * v.y;
        acc.z += nrm * v.z; acc.w += nrm * v.w;
    }
    acc.x += __shfl_xor(acc.x, 32);
    acc.y += __shfl_xor(acc.y, 32);
    acc.z += __shfl_xor(acc.z, 32);
    acc.w += __shfl_xor(acc.w, 32);
    if (half == 0) {
        float4 xc = *reinterpret_cast<const float4*>(xw + (size_t)c * HDIM + hq * 4);
        float di = dinv[c];
        float4 bb = *reinterpret_cast<const float4*>(b + hq * 4);
        *reinterpret_cast<float4*>(out + (size_t)c * HDIM + hq * 4) =
            make_float4(di * xc.x + bb.x + acc.x, di * xc.y + bb.y + acc.y,
                        di * xc.z + bb.z + acc.z, di * xc.w + bb.w + acc.w);
    }
}

// ---------------- graph start offsets (batch is sorted) ----------------
__global__ __launch_bounds__(256) void gstart_k(const int* __restrict__ batch,
                                                int* __restrict__ start, int N, int G) {
    int n = blockIdx.x * 256 + threadIdx.x;
    if (n > N) return;
    if (n < N) {
        int b = batch[n];
        int prev = (n == 0) ? -1 : batch[n - 1];
        for (int g = prev + 1; g <= b; ++g) start[g] = n;
    } else {
        int prev = batch[N - 1];
        for (int g = prev + 1; g <= G; ++g) start[g] = N;
    }
}

// ---------------- fused mean-pool + final linear ----------------
__global__ __launch_bounds__(256) void final_pool_k(const float* __restrict__ h,
                                                    const int* __restrict__ start,
                                                    const float* __restrict__ Wlin,
                                                    const float* __restrict__ blin,
                                                    float* __restrict__ out, int G) {
    int g = blockIdx.x * 4 + (threadIdx.x >> 6);
    int lane = threadIdx.x & 63;
    if (g >= G) return;
    int s = start[g], e = start[g + 1];
    float w0 = Wlin[lane], w1 = Wlin[lane + 64];
    float acc = 0.f;
    for (int n = s; n < e; ++n) {
        const float* p = h + (size_t)n * HDIM;
        acc += p[lane] * w0 + p[lane + 64] * w1;
    }
#pragma unroll
    for (int off = 32; off > 0; off >>= 1) acc += __shfl_down(acc, off);
    if (lane == 0) out[g] = acc / fmaxf((float)(e - s), 1.0f) + blin[0];
}

extern "C" void kernel_launch(void* const* d_in, const int* in_sizes, int n_in,
                              void* d_out, int out_size, void* d_ws, size_t ws_size,
                              hipStream_t stream) {
    const float* x    = (const float*)d_in[0];
    const float* W1   = (const float*)d_in[1];
    const float* b1   = (const float*)d_in[2];
    const float* W2   = (const float*)d_in[3];
    const float* b2   = (const float*)d_in[4];
    const float* W3   = (const float*)d_in[5];
    const float* b3   = (const float*)d_in[6];
    const float* Wlin = (const float*)d_in[7];
    const float* blin = (const float*)d_in[8];
    const int* ei     = (const int*)d_in[9];
    const int* batch  = (const int*)d_in[10];

    const int N = in_sizes[10];
    const int E = in_sizes[9] / 2;
    const int G = out_size;
    const size_t NH = (size_t)N * HDIM;
    const int NB = (N + 255) / 256;               // scan blocks (<=512)

    const int* row = ei;
    const int* col = ei + E;

    // workspace layout (csr first for 8B alignment)
    int2* csr     = (int2*)d_ws;                 // [E]
    float* xw     = (float*)(csr + E);           // [N,H]  (also holds Y[N,32] in layer 1)
    float* bufA   = xw + NH;                     // [N,H]
    float* dis    = bufA + NH;                   // [N]
    float* dinv   = dis + N;                     // [N]
    int* deg_i    = (int*)(dinv + N);            // [N]
    int* row_ptr  = deg_i + N;                   // [N+1]
    int* cursor   = row_ptr + N + 1;             // [N]
    int* gstart   = cursor + N;                  // [G+1]
    int* incl     = gstart + G + 1;              // [N]
    int* partial  = incl + N;                    // [NB]

    float* outf = (float*)d_out;

    // ---- CSR build ----
    hipMemsetAsync(deg_i, 0, (size_t)N * sizeof(int), stream);
    hipMemsetAsync(cursor, 0, (size_t)N * sizeof(int), stream);
    deg_hist_k<<<(E + 255) / 256, 256, 0, stream>>>(col, deg_i, E);
    scan1_k<<<NB, 256, 0, stream>>>(deg_i, incl, partial, dis, dinv, N);
    scan2_k<<<1, 512, 0, stream>>>(partial, NB);
    scan3_k<<<NB, 256, 0, stream>>>(deg_i, incl, partial, row_ptr, N);
    csr_fill_k<<<(E + 255) / 256, 256, 0, stream>>>(row, col, dis, row_ptr, cursor, csr, E);
    gstart_k<<<(N + 256) / 256, 256, 0, stream>>>(batch, gstart, N, G);

    const int gemm_grid = (N + 63) / 64;
    const int wave_grid = (N + 3) / 4;            // one wave (64 thr) per node

    // layer 1 (aggregate-first): Y = A_hat X  (32-dim gather), out1 = Y W1 + b1 -> bufA
    gather_x_k<<<wave_grid, 256, 0, stream>>>(row_ptr, csr, dinv, x, xw, N);
    gemm_gcn<32, false, true><<<gemm_grid, 256, 0, stream>>>(xw, W1, b1, bufA, N);
    // layer 2: relu(bufA) W2 -> xw ; gather(+b2) -> bufA
    gemm_gcn<128, true, false><<<gemm_grid, 256, 0, stream>>>(bufA, W2, nullptr, xw, N);
    gather_k<<<wave_grid, 256, 0, stream>>>(row_ptr, csr, dinv, b2, xw, bufA, N);
    // layer 3: relu(bufA) W3 -> xw ; gather(+b3) -> bufA
    gemm_gcn<128, true, false><<<gemm_grid, 256, 0, stream>>>(bufA, W3, nullptr, xw, N);
    gather_k<<<wave_grid, 256, 0, stream>>>(row_ptr, csr, dinv, b3, xw, bufA, N);

    // fused mean-pool + linear
    final_pool_k<<<(G + 3) / 4, 256, 0, stream>>>(bufA, gstart, Wlin, blin, outf, G);
}

// Round 6
// 531.219 us; speedup vs baseline: 1.1521x; 1.1521x over previous
//
#include <hip/hip_runtime.h>
#include <math.h>

#define HDIM 128

typedef __attribute__((ext_vector_type(8))) short bf16x8;
typedef __attribute__((ext_vector_type(4))) float f32x4;

// RNE split of fp32 into bf16 hi + bf16 lo (x ~= hi + lo, err ~2^-18 |x|)
__device__ __forceinline__ void split_bf16(float x, short& hi, short& lo) {
    unsigned u = __float_as_uint(x);
    unsigned r = (u + 0x7FFFu + ((u >> 16) & 1u)) >> 16;
    float hf = __uint_as_float(r << 16);
    hi = (short)r;
    float l = x - hf;
    unsigned ul = __float_as_uint(l);
    unsigned rl = (ul + 0x7FFFu + ((ul >> 16) & 1u)) >> 16;
    lo = (short)rl;
}

// ---------------- degree histogram (int) ----------------
__global__ __launch_bounds__(256) void deg_hist_k(const int* __restrict__ col,
                                                  int* __restrict__ deg, int E) {
    int e = blockIdx.x * 256 + threadIdx.x;
    if (e < E) atomicAdd(&deg[col[e]], 1);
}

// ---------------- scan1 + degree finish (fused) ----------------
__global__ __launch_bounds__(256) void scan1_k(const int* __restrict__ deg,
                                               int* __restrict__ incl,
                                               int* __restrict__ partial,
                                               float* __restrict__ dis,
                                               float* __restrict__ dinv, int N) {
    int i = blockIdx.x * 256 + threadIdx.x;
    int lane = threadIdx.x & 63;
    int wid = threadIdx.x >> 6;
    int d0 = (i < N) ? deg[i] : 0;
    if (i < N) {
        double d = (double)d0 + 1.0;
        dis[i]  = (float)(1.0 / sqrt(d));
        dinv[i] = (float)(1.0 / d);
    }
    int s = d0;
#pragma unroll
    for (int off = 1; off < 64; off <<= 1) {
        int t = __shfl_up(s, off);
        if (lane >= off) s += t;
    }
    __shared__ int wsum[4];
    if (lane == 63) wsum[wid] = s;
    __syncthreads();
    if (threadIdx.x == 0) {
        int run = 0;
#pragma unroll
        for (int w = 0; w < 4; ++w) { int t = wsum[w]; wsum[w] = run; run += t; }
    }
    __syncthreads();
    s += wsum[wid];
    if (i < N) incl[i] = s;
    if (threadIdx.x == 255) partial[blockIdx.x] = s;
}

__global__ __launch_bounds__(512) void scan2_k(int* __restrict__ partial, int NB) {
    __shared__ int sm[512];
    int t = threadIdx.x;
    sm[t] = (t < NB) ? partial[t] : 0;
    __syncthreads();
    for (int off = 1; off < 512; off <<= 1) {
        int v = (t >= off) ? sm[t - off] : 0;
        __syncthreads();
        sm[t] += v;
        __syncthreads();
    }
    if (t < NB) partial[t] = (t == 0) ? 0 : sm[t - 1];
}

__global__ __launch_bounds__(256) void scan3_k(const int* __restrict__ deg,
                                               const int* __restrict__ incl,
                                               const int* __restrict__ partial,
                                               int* __restrict__ row_ptr, int N) {
    int i = blockIdx.x * 256 + threadIdx.x;
    if (i < N) {
        int off = partial[blockIdx.x];
        row_ptr[i] = incl[i] - deg[i] + off;
        if (i == N - 1) row_ptr[N] = incl[i] + off;
    }
}

// ---------------- CSR fill (counting sort by destination) ----------------
__global__ __launch_bounds__(256) void csr_fill_k(const int* __restrict__ row,
                                                  const int* __restrict__ col,
                                                  const float* __restrict__ dis,
                                                  const int* __restrict__ row_ptr,
                                                  int* __restrict__ cursor,
                                                  int2* __restrict__ csr, int E) {
    int e = blockIdx.x * 256 + threadIdx.x;
    if (e >= E) return;
    int r = row[e], c = col[e];
    int pos = atomicAdd(&cursor[c], 1);
    float nrm = dis[r] * dis[c];
    csr[row_ptr[c] + pos] = make_int2(r, __float_as_int(nrm));
}

// ---------------- split-bf16 MFMA GEMM: out = relu?(X) @ W [+ bias] ----------------
// Block: 256 thr (4 waves), tile 128 rows x 128 cols. W split hi/lo + transposed in LDS.
// Per wave: rows m0..m0+31 (2 row-tiles of 16), all 8 col-tiles.
// X@W ~= hi@hi + hi@lo + lo@hi (3 bf16 MFMA passes, err ~1e-5).
template<int K, bool RELU, bool BIAS>
__global__ __launch_bounds__(256) void gemm_mfma(const float* __restrict__ X,
                                                 const float* __restrict__ W,
                                                 const float* __restrict__ b,
                                                 float* __restrict__ out, int N) {
    constexpr int KP = K + 8;                    // row stride: 16B-aligned, bank-balanced
    __shared__ short whi[HDIM][KP];
    __shared__ short wlo[HDIM][KP];
    const int tid = threadIdx.x;
    for (int i = tid; i < K * HDIM; i += 256) {  // W[k][n] -> whiT[n][k], wloT[n][k]
        int k = i >> 7, n = i & 127;
        short h, l; split_bf16(W[i], h, l);
        whi[n][k] = h; wlo[n][k] = l;
    }
    __syncthreads();

    const int wid = tid >> 6, lane = tid & 63;
    const int lr = lane & 15;                    // frag row (A/M) / col (B,C/N)
    const int lk = (lane >> 4) * 8;              // frag k-offset
    const int m0 = blockIdx.x * 128 + wid * 32;

    f32x4 acc[2][8];
#pragma unroll
    for (int rt = 0; rt < 2; ++rt)
#pragma unroll
        for (int ct = 0; ct < 8; ++ct) acc[rt][ct] = (f32x4){0.f, 0.f, 0.f, 0.f};

#pragma unroll
    for (int ks = 0; ks < K; ks += 32) {
        bf16x8 ahi[2], alo[2];
#pragma unroll
        for (int rt = 0; rt < 2; ++rt) {
            int row = m0 + rt * 16 + lr;
            float v[8] = {0.f, 0.f, 0.f, 0.f, 0.f, 0.f, 0.f, 0.f};
            if (row < N) {
                const float* p = X + (size_t)row * K + ks + lk;
                float4 u0 = *reinterpret_cast<const float4*>(p);
                float4 u1 = *reinterpret_cast<const float4*>(p + 4);
                v[0] = u0.x; v[1] = u0.y; v[2] = u0.z; v[3] = u0.w;
                v[4] = u1.x; v[5] = u1.y; v[6] = u1.z; v[7] = u1.w;
            }
#pragma unroll
            for (int j = 0; j < 8; ++j) {
                float f = RELU ? fmaxf(v[j], 0.f) : v[j];
                short h, l; split_bf16(f, h, l);
                ahi[rt][j] = h; alo[rt][j] = l;
            }
        }
#pragma unroll
        for (int ct = 0; ct < 8; ++ct) {
            bf16x8 bhi = *reinterpret_cast<const bf16x8*>(&whi[ct * 16 + lr][ks + lk]);
            bf16x8 blo = *reinterpret_cast<const bf16x8*>(&wlo[ct * 16 + lr][ks + lk]);
#pragma unroll
            for (int rt = 0; rt < 2; ++rt) {
                acc[rt][ct] = __builtin_amdgcn_mfma_f32_16x16x32_bf16(ahi[rt], bhi, acc[rt][ct], 0, 0, 0);
                acc[rt][ct] = __builtin_amdgcn_mfma_f32_16x16x32_bf16(ahi[rt], blo, acc[rt][ct], 0, 0, 0);
                acc[rt][ct] = __builtin_amdgcn_mfma_f32_16x16x32_bf16(alo[rt], bhi, acc[rt][ct], 0, 0, 0);
            }
        }
    }

    const int r0 = (lane >> 4) * 4;              // C row base within 16x16 tile
#pragma unroll
    for (int ct = 0; ct < 8; ++ct) {
        float bias = BIAS ? b[ct * 16 + lr] : 0.f;
#pragma unroll
        for (int rt = 0; rt < 2; ++rt) {
#pragma unroll
            for (int r = 0; r < 4; ++r) {
                int row = m0 + rt * 16 + r0 + r;
                if (row < N) out[(size_t)row * HDIM + ct * 16 + lr] = acc[rt][ct][r] + bias;
            }
        }
    }
}

// ---------------- 32-dim input gather (octant version, round-4) ----------------
__global__ __launch_bounds__(256) void gather_x_k(const int* __restrict__ row_ptr,
                                                  const int2* __restrict__ csr,
                                                  const float* __restrict__ dinv,
                                                  const float* __restrict__ X,
                                                  float* __restrict__ Y, int N) {
    int idx = blockIdx.x * 256 + threadIdx.x;   // per (node, octant)
    int c = idx >> 3;
    if (c >= N) return;
    int hq = idx & 7;
    int j0 = row_ptr[c], j1 = row_ptr[c + 1];
    float di = dinv[c];
    float4 xc = *reinterpret_cast<const float4*>(X + (size_t)c * 32 + hq * 4);
    float4 acc = make_float4(di * xc.x, di * xc.y, di * xc.z, di * xc.w);
    int j = j0;
    for (; j + 3 < j1; j += 4) {
        int2 e0 = csr[j], e1 = csr[j + 1], e2 = csr[j + 2], e3 = csr[j + 3];
        float4 v0 = *reinterpret_cast<const float4*>(X + (size_t)e0.x * 32 + hq * 4);
        float4 v1 = *reinterpret_cast<const float4*>(X + (size_t)e1.x * 32 + hq * 4);
        float4 v2 = *reinterpret_cast<const float4*>(X + (size_t)e2.x * 32 + hq * 4);
        float4 v3 = *reinterpret_cast<const float4*>(X + (size_t)e3.x * 32 + hq * 4);
        float n0 = __int_as_float(e0.y), n1 = __int_as_float(e1.y);
        float n2 = __int_as_float(e2.y), n3 = __int_as_float(e3.y);
        acc.x += n0 * v0.x + n1 * v1.x + n2 * v2.x + n3 * v3.x;
        acc.y += n0 * v0.y + n1 * v1.y + n2 * v2.y + n3 * v3.y;
        acc.z += n0 * v0.z + n1 * v1.z + n2 * v2.z + n3 * v3.z;
        acc.w += n0 * v0.w + n1 * v1.w + n2 * v2.w + n3 * v3.w;
    }
    for (; j < j1; ++j) {
        int2 en = csr[j];
        float nrm = __int_as_float(en.y);
        float4 v = *reinterpret_cast<const float4*>(X + (size_t)en.x * 32 + hq * 4);
        acc.x += nrm * v.x; acc.y += nrm * v.y;
        acc.z += nrm * v.z; acc.w += nrm * v.w;
    }
    *reinterpret_cast<float4*>(Y + (size_t)c * 32 + hq * 4) = acc;
}

// ---------------- 128-dim gather: one wave per node (round-5, fastest) ----------------
__global__ __launch_bounds__(256) void gather_k(const int* __restrict__ row_ptr,
                                                const int2* __restrict__ csr,
                                                const float* __restrict__ dinv,
                                                const float* __restrict__ b,
                                                const float* __restrict__ xw,
                                                float* __restrict__ out, int N) {
    int c = (blockIdx.x * 256 + threadIdx.x) >> 6;
    if (c >= N) return;
    int lane = threadIdx.x & 63;
    int half = lane >> 5;
    int hq = lane & 31;
    int j0 = row_ptr[c], j1 = row_ptr[c + 1];
    float4 acc = make_float4(0.f, 0.f, 0.f, 0.f);
    int j = j0 + half;
    for (; j + 2 < j1; j += 4) {
        int2 e0 = csr[j], e1 = csr[j + 2];
        float4 v0 = *reinterpret_cast<const float4*>(xw + (size_t)e0.x * HDIM + hq * 4);
        float4 v1 = *reinterpret_cast<const float4*>(xw + (size_t)e1.x * HDIM + hq * 4);
        float n0 = __int_as_float(e0.y), n1 = __int_as_float(e1.y);
        acc.x += n0 * v0.x + n1 * v1.x;
        acc.y += n0 * v0.y + n1 * v1.y;
        acc.z += n0 * v0.z + n1 * v1.z;
        acc.w += n0 * v0.w + n1 * v1.w;
    }
    for (; j < j1; j += 2) {
        int2 en = csr[j];
        float nrm = __int_as_float(en.y);
        float4 v = *reinterpret_cast<const float4*>(xw + (size_t)en.x * HDIM + hq * 4);
        acc.x += nrm * v.x; acc.y += nrm * v.y;
        acc.z += nrm * v.z; acc.w += nrm * v.w;
    }
    acc.x += __shfl_xor(acc.x, 32);
    acc.y += __shfl_xor(acc.y, 32);
    acc.z += __shfl_xor(acc.z, 32);
    acc.w += __shfl_xor(acc.w, 32);
    if (half == 0) {
        float4 xc = *reinterpret_cast<const float4*>(xw + (size_t)c * HDIM + hq * 4);
        float di = dinv[c];
        float4 bb = *reinterpret_cast<const float4*>(b + hq * 4);
        *reinterpret_cast<float4*>(out + (size_t)c * HDIM + hq * 4) =
            make_float4(di * xc.x + bb.x + acc.x, di * xc.y + bb.y + acc.y,
                        di * xc.z + bb.z + acc.z, di * xc.w + bb.w + acc.w);
    }
}

// ---------------- graph start offsets (batch is sorted) ----------------
__global__ __launch_bounds__(256) void gstart_k(const int* __restrict__ batch,
                                                int* __restrict__ start, int N, int G) {
    int n = blockIdx.x * 256 + threadIdx.x;
    if (n > N) return;
    if (n < N) {
        int b = batch[n];
        int prev = (n == 0) ? -1 : batch[n - 1];
        for (int g = prev + 1; g <= b; ++g) start[g] = n;
    } else {
        int prev = batch[N - 1];
        for (int g = prev + 1; g <= G; ++g) start[g] = N;
    }
}

// ---------------- fused mean-pool + final linear ----------------
__global__ __launch_bounds__(256) void final_pool_k(const float* __restrict__ h,
                                                    const int* __restrict__ start,
                                                    const float* __restrict__ Wlin,
                                                    const float* __restrict__ blin,
                                                    float* __restrict__ out, int G) {
    int g = blockIdx.x * 4 + (threadIdx.x >> 6);
    int lane = threadIdx.x & 63;
    if (g >= G) return;
    int s = start[g], e = start[g + 1];
    float w0 = Wlin[lane], w1 = Wlin[lane + 64];
    float acc = 0.f;
    for (int n = s; n < e; ++n) {
        const float* p = h + (size_t)n * HDIM;
        acc += p[lane] * w0 + p[lane + 64] * w1;
    }
#pragma unroll
    for (int off = 32; off > 0; off >>= 1) acc += __shfl_down(acc, off);
    if (lane == 0) out[g] = acc / fmaxf((float)(e - s), 1.0f) + blin[0];
}

extern "C" void kernel_launch(void* const* d_in, const int* in_sizes, int n_in,
                              void* d_out, int out_size, void* d_ws, size_t ws_size,
                              hipStream_t stream) {
    const float* x    = (const float*)d_in[0];
    const float* W1   = (const float*)d_in[1];
    const float* b1   = (const float*)d_in[2];
    const float* W2   = (const float*)d_in[3];
    const float* b2   = (const float*)d_in[4];
    const float* W3   = (const float*)d_in[5];
    const float* b3   = (const float*)d_in[6];
    const float* Wlin = (const float*)d_in[7];
    const float* blin = (const float*)d_in[8];
    const int* ei     = (const int*)d_in[9];
    const int* batch  = (const int*)d_in[10];

    const int N = in_sizes[10];
    const int E = in_sizes[9] / 2;
    const int G = out_size;
    const size_t NH = (size_t)N * HDIM;
    const int NB = (N + 255) / 256;

    const int* row = ei;
    const int* col = ei + E;

    int2* csr     = (int2*)d_ws;                 // [E]
    float* xw     = (float*)(csr + E);           // [N,H] (also Y[N,32] in layer 1)
    float* bufA   = xw + NH;                     // [N,H]
    float* dis    = bufA + NH;                   // [N]
    float* dinv   = dis + N;                     // [N]
    int* deg_i    = (int*)(dinv + N);            // [N]
    int* row_ptr  = deg_i + N;                   // [N+1]
    int* cursor   = row_ptr + N + 1;             // [N]
    int* gstart   = cursor + N;                  // [G+1]
    int* incl     = gstart + G + 1;              // [N]
    int* partial  = incl + N;                    // [NB]

    float* outf = (float*)d_out;

    // ---- CSR build ----
    hipMemsetAsync(deg_i, 0, (size_t)N * sizeof(int), stream);
    hipMemsetAsync(cursor, 0, (size_t)N * sizeof(int), stream);
    deg_hist_k<<<(E + 255) / 256, 256, 0, stream>>>(col, deg_i, E);
    scan1_k<<<NB, 256, 0, stream>>>(deg_i, incl, partial, dis, dinv, N);
    scan2_k<<<1, 512, 0, stream>>>(partial, NB);
    scan3_k<<<NB, 256, 0, stream>>>(deg_i, incl, partial, row_ptr, N);
    csr_fill_k<<<(E + 255) / 256, 256, 0, stream>>>(row, col, dis, row_ptr, cursor, csr, E);
    gstart_k<<<(N + 256) / 256, 256, 0, stream>>>(batch, gstart, N, G);

    const int mfma_grid = (N + 127) / 128;
    const int wave_grid = (N + 3) / 4;

    // layer 1 (aggregate-first): Y = A_hat X (32-dim gather); out1 = Y W1 + b1
    gather_x_k<<<(N * 8 + 255) / 256, 256, 0, stream>>>(row_ptr, csr, dinv, x, xw, N);
    gemm_mfma<32, false, true><<<mfma_grid, 256, 0, stream>>>(xw, W1, b1, bufA, N);
    // layer 2: relu(bufA) W2 -> xw ; gather(+b2) -> bufA
    gemm_mfma<128, true, false><<<mfma_grid, 256, 0, stream>>>(bufA, W2, nullptr, xw, N);
    gather_k<<<wave_grid, 256, 0, stream>>>(row_ptr, csr, dinv, b2, xw, bufA, N);
    // layer 3: relu(bufA) W3 -> xw ; gather(+b3) -> bufA
    gemm_mfma<128, true, false><<<mfma_grid, 256, 0, stream>>>(bufA, W3, nullptr, xw, N);
    gather_k<<<wave_grid, 256, 0, stream>>>(row_ptr, csr, dinv, b3, xw, bufA, N);

    // fused mean-pool + linear
    final_pool_k<<<(G + 3) / 4, 256, 0, stream>>>(bufA, gstart, Wlin, blin, outf, G);
}

// Round 7
// 384.351 us; speedup vs baseline: 1.5924x; 1.3821x over previous
//
#include <hip/hip_runtime.h>
#include <math.h>

#define HDIM 128

typedef __attribute__((ext_vector_type(8))) short bf16x8;
typedef __attribute__((ext_vector_type(4))) float f32x4;

// RNE split of fp32 into bf16 hi + bf16 lo (x ~= hi + lo, err ~2^-18 |x|)
__device__ __forceinline__ void split_bf16(float x, short& hi, short& lo) {
    unsigned u = __float_as_uint(x);
    unsigned r = (u + 0x7FFFu + ((u >> 16) & 1u)) >> 16;
    float hf = __uint_as_float(r << 16);
    hi = (short)r;
    float l = x - hf;
    unsigned ul = __float_as_uint(l);
    unsigned rl = (ul + 0x7FFFu + ((ul >> 16) & 1u)) >> 16;
    lo = (short)rl;
}

// ---------------- degree histogram (int) ----------------
__global__ __launch_bounds__(256) void deg_hist_k(const int* __restrict__ col,
                                                  int* __restrict__ deg, int E) {
    int e = blockIdx.x * 256 + threadIdx.x;
    if (e < E) atomicAdd(&deg[col[e]], 1);
}

// ---------------- scan1 + degree finish (fused) ----------------
__global__ __launch_bounds__(256) void scan1_k(const int* __restrict__ deg,
                                               int* __restrict__ incl,
                                               int* __restrict__ partial,
                                               float* __restrict__ dis,
                                               float* __restrict__ dinv, int N) {
    int i = blockIdx.x * 256 + threadIdx.x;
    int lane = threadIdx.x & 63;
    int wid = threadIdx.x >> 6;
    int d0 = (i < N) ? deg[i] : 0;
    if (i < N) {
        double d = (double)d0 + 1.0;
        dis[i]  = (float)(1.0 / sqrt(d));
        dinv[i] = (float)(1.0 / d);
    }
    int s = d0;
#pragma unroll
    for (int off = 1; off < 64; off <<= 1) {
        int t = __shfl_up(s, off);
        if (lane >= off) s += t;
    }
    __shared__ int wsum[4];
    if (lane == 63) wsum[wid] = s;
    __syncthreads();
    if (threadIdx.x == 0) {
        int run = 0;
#pragma unroll
        for (int w = 0; w < 4; ++w) { int t = wsum[w]; wsum[w] = run; run += t; }
    }
    __syncthreads();
    s += wsum[wid];
    if (i < N) incl[i] = s;
    if (threadIdx.x == 255) partial[blockIdx.x] = s;
}

__global__ __launch_bounds__(512) void scan2_k(int* __restrict__ partial, int NB) {
    __shared__ int sm[512];
    int t = threadIdx.x;
    sm[t] = (t < NB) ? partial[t] : 0;
    __syncthreads();
    for (int off = 1; off < 512; off <<= 1) {
        int v = (t >= off) ? sm[t - off] : 0;
        __syncthreads();
        sm[t] += v;
        __syncthreads();
    }
    if (t < NB) partial[t] = (t == 0) ? 0 : sm[t - 1];
}

__global__ __launch_bounds__(256) void scan3_k(const int* __restrict__ deg,
                                               const int* __restrict__ incl,
                                               const int* __restrict__ partial,
                                               int* __restrict__ row_ptr, int N) {
    int i = blockIdx.x * 256 + threadIdx.x;
    if (i < N) {
        int off = partial[blockIdx.x];
        row_ptr[i] = incl[i] - deg[i] + off;
        if (i == N - 1) row_ptr[N] = incl[i] + off;
    }
}

// ---------------- CSR fill (counting sort by destination) ----------------
__global__ __launch_bounds__(256) void csr_fill_k(const int* __restrict__ row,
                                                  const int* __restrict__ col,
                                                  const float* __restrict__ dis,
                                                  const int* __restrict__ row_ptr,
                                                  int* __restrict__ cursor,
                                                  int2* __restrict__ csr, int E) {
    int e = blockIdx.x * 256 + threadIdx.x;
    if (e >= E) return;
    int r = row[e], c = col[e];
    int pos = atomicAdd(&cursor[c], 1);
    float nrm = dis[r] * dis[c];
    csr[row_ptr[c] + pos] = make_int2(r, __float_as_int(nrm));
}

// ---------------- split-bf16 MFMA GEMM: out = relu?(X) @ W [+ bias] ----------------
template<int K, bool RELU, bool BIAS>
__global__ __launch_bounds__(256) void gemm_mfma(const float* __restrict__ X,
                                                 const float* __restrict__ W,
                                                 const float* __restrict__ b,
                                                 float* __restrict__ out, int N) {
    constexpr int KP = K + 8;
    __shared__ short whi[HDIM][KP];
    __shared__ short wlo[HDIM][KP];
    const int tid = threadIdx.x;
    for (int i = tid; i < K * HDIM; i += 256) {  // W[k][n] -> whiT[n][k], wloT[n][k]
        int k = i >> 7, n = i & 127;
        short h, l; split_bf16(W[i], h, l);
        whi[n][k] = h; wlo[n][k] = l;
    }
    __syncthreads();

    const int wid = tid >> 6, lane = tid & 63;
    const int lr = lane & 15;
    const int lk = (lane >> 4) * 8;
    const int m0 = blockIdx.x * 128 + wid * 32;

    f32x4 acc[2][8];
#pragma unroll
    for (int rt = 0; rt < 2; ++rt)
#pragma unroll
        for (int ct = 0; ct < 8; ++ct) acc[rt][ct] = (f32x4){0.f, 0.f, 0.f, 0.f};

#pragma unroll
    for (int ks = 0; ks < K; ks += 32) {
        bf16x8 ahi[2], alo[2];
#pragma unroll
        for (int rt = 0; rt < 2; ++rt) {
            int row = m0 + rt * 16 + lr;
            float v[8] = {0.f, 0.f, 0.f, 0.f, 0.f, 0.f, 0.f, 0.f};
            if (row < N) {
                const float* p = X + (size_t)row * K + ks + lk;
                float4 u0 = *reinterpret_cast<const float4*>(p);
                float4 u1 = *reinterpret_cast<const float4*>(p + 4);
                v[0] = u0.x; v[1] = u0.y; v[2] = u0.z; v[3] = u0.w;
                v[4] = u1.x; v[5] = u1.y; v[6] = u1.z; v[7] = u1.w;
            }
#pragma unroll
            for (int j = 0; j < 8; ++j) {
                float f = RELU ? fmaxf(v[j], 0.f) : v[j];
                short h, l; split_bf16(f, h, l);
                ahi[rt][j] = h; alo[rt][j] = l;
            }
        }
#pragma unroll
        for (int ct = 0; ct < 8; ++ct) {
            bf16x8 bhi = *reinterpret_cast<const bf16x8*>(&whi[ct * 16 + lr][ks + lk]);
            bf16x8 blo = *reinterpret_cast<const bf16x8*>(&wlo[ct * 16 + lr][ks + lk]);
#pragma unroll
            for (int rt = 0; rt < 2; ++rt) {
                acc[rt][ct] = __builtin_amdgcn_mfma_f32_16x16x32_bf16(ahi[rt], bhi, acc[rt][ct], 0, 0, 0);
                acc[rt][ct] = __builtin_amdgcn_mfma_f32_16x16x32_bf16(ahi[rt], blo, acc[rt][ct], 0, 0, 0);
                acc[rt][ct] = __builtin_amdgcn_mfma_f32_16x16x32_bf16(alo[rt], bhi, acc[rt][ct], 0, 0, 0);
            }
        }
    }

    const int r0 = (lane >> 4) * 4;
#pragma unroll
    for (int ct = 0; ct < 8; ++ct) {
        float bias = BIAS ? b[ct * 16 + lr] : 0.f;
#pragma unroll
        for (int rt = 0; rt < 2; ++rt) {
#pragma unroll
            for (int r = 0; r < 4; ++r) {
                int row = m0 + rt * 16 + r0 + r;
                if (row < N) out[(size_t)row * HDIM + ct * 16 + lr] = acc[rt][ct][r] + bias;
            }
        }
    }
}

// ---------------- 32-dim input gather (octant version) ----------------
__global__ __launch_bounds__(256) void gather_x_k(const int* __restrict__ row_ptr,
                                                  const int2* __restrict__ csr,
                                                  const float* __restrict__ dinv,
                                                  const float* __restrict__ X,
                                                  float* __restrict__ Y, int N) {
    int idx = blockIdx.x * 256 + threadIdx.x;
    int c = idx >> 3;
    if (c >= N) return;
    int hq = idx & 7;
    int j0 = row_ptr[c], j1 = row_ptr[c + 1];
    float di = dinv[c];
    float4 xc = *reinterpret_cast<const float4*>(X + (size_t)c * 32 + hq * 4);
    float4 acc = make_float4(di * xc.x, di * xc.y, di * xc.z, di * xc.w);
    int j = j0;
    for (; j + 3 < j1; j += 4) {
        int2 e0 = csr[j], e1 = csr[j + 1], e2 = csr[j + 2], e3 = csr[j + 3];
        float4 v0 = *reinterpret_cast<const float4*>(X + (size_t)e0.x * 32 + hq * 4);
        float4 v1 = *reinterpret_cast<const float4*>(X + (size_t)e1.x * 32 + hq * 4);
        float4 v2 = *reinterpret_cast<const float4*>(X + (size_t)e2.x * 32 + hq * 4);
        float4 v3 = *reinterpret_cast<const float4*>(X + (size_t)e3.x * 32 + hq * 4);
        float n0 = __int_as_float(e0.y), n1 = __int_as_float(e1.y);
        float n2 = __int_as_float(e2.y), n3 = __int_as_float(e3.y);
        acc.x += n0 * v0.x + n1 * v1.x + n2 * v2.x + n3 * v3.x;
        acc.y += n0 * v0.y + n1 * v1.y + n2 * v2.y + n3 * v3.y;
        acc.z += n0 * v0.z + n1 * v1.z + n2 * v2.z + n3 * v3.z;
        acc.w += n0 * v0.w + n1 * v1.w + n2 * v2.w + n3 * v3.w;
    }
    for (; j < j1; ++j) {
        int2 en = csr[j];
        float nrm = __int_as_float(en.y);
        float4 v = *reinterpret_cast<const float4*>(X + (size_t)en.x * 32 + hq * 4);
        acc.x += nrm * v.x; acc.y += nrm * v.y;
        acc.z += nrm * v.z; acc.w += nrm * v.w;
    }
    *reinterpret_cast<float4*>(Y + (size_t)c * 32 + hq * 4) = acc;
}

// ---------------- w3l = W3 @ Wlin ; consts[0] = b3.Wlin + blin ----------------
__global__ __launch_bounds__(128) void w3l_k(const float* __restrict__ W3,
                                             const float* __restrict__ b3,
                                             const float* __restrict__ Wlin,
                                             const float* __restrict__ blin,
                                             float* __restrict__ w3l,
                                             float* __restrict__ consts) {
    __shared__ float wl[128];
    __shared__ float red[128];
    int t = threadIdx.x;
    wl[t] = Wlin[t];
    __syncthreads();
    float a = 0.f;
    for (int j = 0; j < 128; ++j) a += W3[t * 128 + j] * wl[j];
    w3l[t] = a;
    red[t] = b3[t] * wl[t];
    __syncthreads();
    for (int off = 64; off > 0; off >>= 1) {
        if (t < off) red[t] += red[t + off];
        __syncthreads();
    }
    if (t == 0) consts[0] = red[0] + blin[0];
}

// ---------------- fused layer-2 gather + z projection ----------------
// one wave per node; h2 row stays in registers; writes only z[c] = relu(h2).w3l
__global__ __launch_bounds__(256) void gather_z_k(const int* __restrict__ row_ptr,
                                                  const int2* __restrict__ csr,
                                                  const float* __restrict__ dinv,
                                                  const float* __restrict__ b,
                                                  const float* __restrict__ xw,
                                                  const float* __restrict__ w3l,
                                                  float* __restrict__ z, int N) {
    int c = (blockIdx.x * 256 + threadIdx.x) >> 6;
    if (c >= N) return;
    int lane = threadIdx.x & 63;
    int half = lane >> 5;
    int hq = lane & 31;
    int j0 = row_ptr[c], j1 = row_ptr[c + 1];
    float4 acc = make_float4(0.f, 0.f, 0.f, 0.f);
    int j = j0 + half;
    for (; j + 2 < j1; j += 4) {
        int2 e0 = csr[j], e1 = csr[j + 2];
        float4 v0 = *reinterpret_cast<const float4*>(xw + (size_t)e0.x * HDIM + hq * 4);
        float4 v1 = *reinterpret_cast<const float4*>(xw + (size_t)e1.x * HDIM + hq * 4);
        float n0 = __int_as_float(e0.y), n1 = __int_as_float(e1.y);
        acc.x += n0 * v0.x + n1 * v1.x;
        acc.y += n0 * v0.y + n1 * v1.y;
        acc.z += n0 * v0.z + n1 * v1.z;
        acc.w += n0 * v0.w + n1 * v1.w;
    }
    for (; j < j1; j += 2) {
        int2 en = csr[j];
        float nrm = __int_as_float(en.y);
        float4 v = *reinterpret_cast<const float4*>(xw + (size_t)en.x * HDIM + hq * 4);
        acc.x += nrm * v.x; acc.y += nrm * v.y;
        acc.z += nrm * v.z; acc.w += nrm * v.w;
    }
    acc.x += __shfl_xor(acc.x, 32);
    acc.y += __shfl_xor(acc.y, 32);
    acc.z += __shfl_xor(acc.z, 32);
    acc.w += __shfl_xor(acc.w, 32);
    // epilogue: h2 quad -> relu -> dot with w3l quad (both halves hold identical totals)
    float4 xc = *reinterpret_cast<const float4*>(xw + (size_t)c * HDIM + hq * 4);
    float di = dinv[c];
    float4 bb = *reinterpret_cast<const float4*>(b + hq * 4);
    float4 wv = *reinterpret_cast<const float4*>(w3l + hq * 4);
    float t = fmaxf(di * xc.x + bb.x + acc.x, 0.f) * wv.x
            + fmaxf(di * xc.y + bb.y + acc.y, 0.f) * wv.y
            + fmaxf(di * xc.z + bb.z + acc.z, 0.f) * wv.z
            + fmaxf(di * xc.w + bb.w + acc.w, 0.f) * wv.w;
#pragma unroll
    for (int off = 1; off < 32; off <<= 1) t += __shfl_xor(t, off);
    if (lane == 0) z[c] = t;
}

// ---------------- scalar layer-3 gather: s[c] = dinv[c]z[c] + sum nrm z[r] ----------------
__global__ __launch_bounds__(256) void gather_s_k(const int* __restrict__ row_ptr,
                                                  const int2* __restrict__ csr,
                                                  const float* __restrict__ dinv,
                                                  const float* __restrict__ z,
                                                  float* __restrict__ s, int N) {
    int c = blockIdx.x * 256 + threadIdx.x;
    if (c >= N) return;
    int j0 = row_ptr[c], j1 = row_ptr[c + 1];
    float acc = dinv[c] * z[c];
    for (int j = j0; j < j1; ++j) {
        int2 en = csr[j];
        acc += __int_as_float(en.y) * z[en.x];
    }
    s[c] = acc;
}

// ---------------- graph start offsets (batch is sorted) ----------------
__global__ __launch_bounds__(256) void gstart_k(const int* __restrict__ batch,
                                                int* __restrict__ start, int N, int G) {
    int n = blockIdx.x * 256 + threadIdx.x;
    if (n > N) return;
    if (n < N) {
        int b = batch[n];
        int prev = (n == 0) ? -1 : batch[n - 1];
        for (int g = prev + 1; g <= b; ++g) start[g] = n;
    } else {
        int prev = batch[N - 1];
        for (int g = prev + 1; g <= G; ++g) start[g] = N;
    }
}

// ---------------- final: out[g] = mean_{c in g} s[c] + consts[0] (empty -> blin) ----------------
__global__ __launch_bounds__(256) void final_z_k(const float* __restrict__ s,
                                                 const int* __restrict__ start,
                                                 const float* __restrict__ consts,
                                                 const float* __restrict__ blin,
                                                 float* __restrict__ out, int G) {
    int g = blockIdx.x * 4 + (threadIdx.x >> 6);
    int lane = threadIdx.x & 63;
    if (g >= G) return;
    int a = start[g], e = start[g + 1];
    float acc = 0.f;
    for (int n = a + lane; n < e; n += 64) acc += s[n];
#pragma unroll
    for (int off = 32; off > 0; off >>= 1) acc += __shfl_down(acc, off);
    if (lane == 0) out[g] = (e > a) ? acc / (float)(e - a) + consts[0] : blin[0];
}

extern "C" void kernel_launch(void* const* d_in, const int* in_sizes, int n_in,
                              void* d_out, int out_size, void* d_ws, size_t ws_size,
                              hipStream_t stream) {
    const float* x    = (const float*)d_in[0];
    const float* W1   = (const float*)d_in[1];
    const float* b1   = (const float*)d_in[2];
    const float* W2   = (const float*)d_in[3];
    const float* b2   = (const float*)d_in[4];
    const float* W3   = (const float*)d_in[5];
    const float* b3   = (const float*)d_in[6];
    const float* Wlin = (const float*)d_in[7];
    const float* blin = (const float*)d_in[8];
    const int* ei     = (const int*)d_in[9];
    const int* batch  = (const int*)d_in[10];

    const int N = in_sizes[10];
    const int E = in_sizes[9] / 2;
    const int G = out_size;
    const size_t NH = (size_t)N * HDIM;
    const int NB = (N + 255) / 256;

    const int* row = ei;
    const int* col = ei + E;

    int2* csr     = (int2*)d_ws;                 // [E]
    float* xw     = (float*)(csr + E);           // [N,H] (Y[N,32] in layer 1, xw2 in layer 2)
    float* bufA   = xw + NH;                     // [N,H] (h1)
    float* dis    = bufA + NH;                   // [N]
    float* dinv   = dis + N;                     // [N]
    float* zbuf   = dinv + N;                    // [N]
    float* sbuf   = zbuf + N;                    // [N]
    float* w3l    = sbuf + N;                    // [128]
    float* consts = w3l + 128;                   // [1]
    int* deg_i    = (int*)(consts + 1);          // [N]
    int* row_ptr  = deg_i + N;                   // [N+1]
    int* cursor   = row_ptr + N + 1;             // [N]
    int* gstart   = cursor + N;                  // [G+1]
    int* incl     = gstart + G + 1;              // [N]
    int* partial  = incl + N;                    // [NB]

    float* outf = (float*)d_out;

    // ---- CSR build ----
    hipMemsetAsync(deg_i, 0, (size_t)N * sizeof(int), stream);
    hipMemsetAsync(cursor, 0, (size_t)N * sizeof(int), stream);
    deg_hist_k<<<(E + 255) / 256, 256, 0, stream>>>(col, deg_i, E);
    scan1_k<<<NB, 256, 0, stream>>>(deg_i, incl, partial, dis, dinv, N);
    scan2_k<<<1, 512, 0, stream>>>(partial, NB);
    scan3_k<<<NB, 256, 0, stream>>>(deg_i, incl, partial, row_ptr, N);
    csr_fill_k<<<(E + 255) / 256, 256, 0, stream>>>(row, col, dis, row_ptr, cursor, csr, E);
    gstart_k<<<(N + 256) / 256, 256, 0, stream>>>(batch, gstart, N, G);
    w3l_k<<<1, 128, 0, stream>>>(W3, b3, Wlin, blin, w3l, consts);

    const int mfma_grid = (N + 127) / 128;
    const int wave_grid = (N + 3) / 4;

    // layer 1 (aggregate-first): Y = A_hat X (32-dim gather); h1 = Y W1 + b1
    gather_x_k<<<(N * 8 + 255) / 256, 256, 0, stream>>>(row_ptr, csr, dinv, x, xw, N);
    gemm_mfma<32, false, true><<<mfma_grid, 256, 0, stream>>>(xw, W1, b1, bufA, N);
    // layer 2: xw2 = relu(h1) W2 ; fused gather(+b2) + z = relu(h2).w3l
    gemm_mfma<128, true, false><<<mfma_grid, 256, 0, stream>>>(bufA, W2, nullptr, xw, N);
    gather_z_k<<<wave_grid, 256, 0, stream>>>(row_ptr, csr, dinv, b2, xw, w3l, zbuf, N);
    // layer 3 (collapsed): s = dinv*z + A-gather(z)
    gather_s_k<<<(N + 255) / 256, 256, 0, stream>>>(row_ptr, csr, dinv, zbuf, sbuf, N);
    // final: segment mean + consts
    final_z_k<<<(G + 3) / 4, 256, 0, stream>>>(sbuf, gstart, consts, blin, outf, G);
}

// Round 9
// 343.621 us; speedup vs baseline: 1.7811x; 1.1185x over previous
//
#include <hip/hip_runtime.h>
#include <math.h>

#define HDIM 128

typedef __attribute__((ext_vector_type(8))) short bf16x8;
typedef __attribute__((ext_vector_type(4))) float f32x4;
typedef __attribute__((ext_vector_type(4))) _Float16 h16x4;

// RNE split of fp32 into bf16 hi + bf16 lo (x ~= hi + lo, err ~2^-16 |x|)
__device__ __forceinline__ void split_bf16(float x, short& hi, short& lo) {
    unsigned u = __float_as_uint(x);
    unsigned r = (u + 0x7FFFu + ((u >> 16) & 1u)) >> 16;
    float hf = __uint_as_float(r << 16);
    hi = (short)r;
    float l = x - hf;
    unsigned ul = __float_as_uint(l);
    unsigned rl = (ul + 0x7FFFu + ((ul >> 16) & 1u)) >> 16;
    lo = (short)rl;
}

// ---------------- degree histogram (int) ----------------
__global__ __launch_bounds__(256) void deg_hist_k(const int* __restrict__ col,
                                                  int* __restrict__ deg, int E) {
    int e = blockIdx.x * 256 + threadIdx.x;
    if (e < E) atomicAdd(&deg[col[e]], 1);
}

// ---------------- scan1 + degree finish (fused) ----------------
__global__ __launch_bounds__(256) void scan1_k(const int* __restrict__ deg,
                                               int* __restrict__ incl,
                                               int* __restrict__ partial,
                                               float* __restrict__ dis,
                                               float* __restrict__ dinv, int N) {
    int i = blockIdx.x * 256 + threadIdx.x;
    int lane = threadIdx.x & 63;
    int wid = threadIdx.x >> 6;
    int d0 = (i < N) ? deg[i] : 0;
    if (i < N) {
        double d = (double)d0 + 1.0;
        dis[i]  = (float)(1.0 / sqrt(d));
        dinv[i] = (float)(1.0 / d);
    }
    int s = d0;
#pragma unroll
    for (int off = 1; off < 64; off <<= 1) {
        int t = __shfl_up(s, off);
        if (lane >= off) s += t;
    }
    __shared__ int wsum[4];
    if (lane == 63) wsum[wid] = s;
    __syncthreads();
    if (threadIdx.x == 0) {
        int run = 0;
#pragma unroll
        for (int w = 0; w < 4; ++w) { int t = wsum[w]; wsum[w] = run; run += t; }
    }
    __syncthreads();
    s += wsum[wid];
    if (i < N) incl[i] = s;
    if (threadIdx.x == 255) partial[blockIdx.x] = s;
}

__global__ __launch_bounds__(512) void scan2_k(int* __restrict__ partial, int NB) {
    __shared__ int sm[512];
    int t = threadIdx.x;
    sm[t] = (t < NB) ? partial[t] : 0;
    __syncthreads();
    for (int off = 1; off < 512; off <<= 1) {
        int v = (t >= off) ? sm[t - off] : 0;
        __syncthreads();
        sm[t] += v;
        __syncthreads();
    }
    if (t < NB) partial[t] = (t == 0) ? 0 : sm[t - 1];
}

__global__ __launch_bounds__(256) void scan3_k(const int* __restrict__ deg,
                                               const int* __restrict__ incl,
                                               const int* __restrict__ partial,
                                               int* __restrict__ row_ptr, int N) {
    int i = blockIdx.x * 256 + threadIdx.x;
    if (i < N) {
        int off = partial[blockIdx.x];
        row_ptr[i] = incl[i] - deg[i] + off;
        if (i == N - 1) row_ptr[N] = incl[i] + off;
    }
}

// ---------------- CSR fill (counting sort by destination) ----------------
__global__ __launch_bounds__(256) void csr_fill_k(const int* __restrict__ row,
                                                  const int* __restrict__ col,
                                                  const float* __restrict__ dis,
                                                  const int* __restrict__ row_ptr,
                                                  int* __restrict__ cursor,
                                                  int2* __restrict__ csr, int E) {
    int e = blockIdx.x * 256 + threadIdx.x;
    if (e >= E) return;
    int r = row[e], c = col[e];
    int pos = atomicAdd(&cursor[c], 1);
    float nrm = dis[r] * dis[c];
    csr[row_ptr[c] + pos] = make_int2(r, __float_as_int(nrm));
}

// ---------------- W pre-split: W[K][128] -> T_hi/lo[n][k] (bf16 shorts) ----------------
__global__ __launch_bounds__(256) void wsplit_k(const float* __restrict__ W,
                                                short* __restrict__ Thi,
                                                short* __restrict__ Tlo, int K) {
    int idx = blockIdx.x * 256 + threadIdx.x;
    if (idx < K * 128) {
        int k = idx >> 7, n = idx & 127;
        short h, l; split_bf16(W[idx], h, l);
        Thi[n * K + k] = h; Tlo[n * K + k] = l;
    }
}

// ---------------- chunked split-bf16 MFMA GEMM ----------------
// out = relu?(X) @ W [+ bias]; X fp32 [N][K]; W pre-split transposed [128][K].
// 256 thr / 4 waves; tile 128 rows x 128 cols; K staged in 32-chunks (40 KB LDS).
template<int K, bool RELU, bool BIAS, bool OUTH>
__global__ __launch_bounds__(256) void gemm_mfma2(const float* __restrict__ X,
                                                  const short* __restrict__ WThi,
                                                  const short* __restrict__ WTlo,
                                                  const float* __restrict__ b,
                                                  float* __restrict__ outF,
                                                  _Float16* __restrict__ outH, int N) {
    constexpr int KP = 40;                       // shorts per LDS row (80 B, 16B-aligned)
    __shared__ short ahi[128][KP], alo[128][KP];
    __shared__ short bhi[128][KP], blo[128][KP];
    const int tid = threadIdx.x;
    const int wid = tid >> 6, lane = tid & 63;
    const int lr = lane & 15;
    const int lk = (lane >> 4) * 8;
    const int m0b = blockIdx.x * 128;

    f32x4 acc[2][8];
#pragma unroll
    for (int rt = 0; rt < 2; ++rt)
#pragma unroll
        for (int ct = 0; ct < 8; ++ct) acc[rt][ct] = (f32x4){0.f, 0.f, 0.f, 0.f};

    for (int ch = 0; ch < K / 32; ++ch) {
        __syncthreads();
        // stage A chunk: rows 0..127, k = ch*32..+32 (coalesced float4), split to hi/lo
#pragma unroll
        for (int i = 0; i < 4; ++i) {
            int f = tid + i * 256;               // 0..1023
            int r = f >> 3, kq = f & 7;
            int grow = m0b + r;
            float4 v = make_float4(0.f, 0.f, 0.f, 0.f);
            if (grow < N) v = *reinterpret_cast<const float4*>(X + (size_t)grow * K + ch * 32 + kq * 4);
            if (RELU) {
                v.x = fmaxf(v.x, 0.f); v.y = fmaxf(v.y, 0.f);
                v.z = fmaxf(v.z, 0.f); v.w = fmaxf(v.w, 0.f);
            }
            short h0, l0, h1, l1;
            split_bf16(v.x, h0, l0); split_bf16(v.y, h1, l1);
            *reinterpret_cast<unsigned*>(&ahi[r][kq * 4]) = (unsigned short)h0 | ((unsigned)(unsigned short)h1 << 16);
            *reinterpret_cast<unsigned*>(&alo[r][kq * 4]) = (unsigned short)l0 | ((unsigned)(unsigned short)l1 << 16);
            split_bf16(v.z, h0, l0); split_bf16(v.w, h1, l1);
            *reinterpret_cast<unsigned*>(&ahi[r][kq * 4 + 2]) = (unsigned short)h0 | ((unsigned)(unsigned short)h1 << 16);
            *reinterpret_cast<unsigned*>(&alo[r][kq * 4 + 2]) = (unsigned short)l0 | ((unsigned)(unsigned short)l1 << 16);
        }
        // stage B chunk: pre-split WT rows n=0..127, 32 shorts/row via 16B copies
#pragma unroll
        for (int i = 0; i < 2; ++i) {
            int f = tid + i * 256;               // 0..511
            int n = f >> 2, k8 = (f & 3) * 8;
            *reinterpret_cast<uint4*>(&bhi[n][k8]) =
                *reinterpret_cast<const uint4*>(WThi + (size_t)n * K + ch * 32 + k8);
            *reinterpret_cast<uint4*>(&blo[n][k8]) =
                *reinterpret_cast<const uint4*>(WTlo + (size_t)n * K + ch * 32 + k8);
        }
        __syncthreads();

        bf16x8 Ahi[2], Alo[2];
#pragma unroll
        for (int rt = 0; rt < 2; ++rt) {
            int arow = wid * 32 + rt * 16 + lr;
            Ahi[rt] = *reinterpret_cast<const bf16x8*>(&ahi[arow][lk]);
            Alo[rt] = *reinterpret_cast<const bf16x8*>(&alo[arow][lk]);
        }
#pragma unroll
        for (int ct = 0; ct < 8; ++ct) {
            bf16x8 Bhi = *reinterpret_cast<const bf16x8*>(&bhi[ct * 16 + lr][lk]);
            bf16x8 Blo = *reinterpret_cast<const bf16x8*>(&blo[ct * 16 + lr][lk]);
#pragma unroll
            for (int rt = 0; rt < 2; ++rt) {
                acc[rt][ct] = __builtin_amdgcn_mfma_f32_16x16x32_bf16(Ahi[rt], Bhi, acc[rt][ct], 0, 0, 0);
                acc[rt][ct] = __builtin_amdgcn_mfma_f32_16x16x32_bf16(Ahi[rt], Blo, acc[rt][ct], 0, 0, 0);
                acc[rt][ct] = __builtin_amdgcn_mfma_f32_16x16x32_bf16(Alo[rt], Bhi, acc[rt][ct], 0, 0, 0);
            }
        }
    }

    const int r0 = (lane >> 4) * 4;
#pragma unroll
    for (int ct = 0; ct < 8; ++ct) {
        float bias = BIAS ? b[ct * 16 + lr] : 0.f;
#pragma unroll
        for (int rt = 0; rt < 2; ++rt) {
#pragma unroll
            for (int r = 0; r < 4; ++r) {
                int row = m0b + wid * 32 + rt * 16 + r0 + r;
                if (row < N) {
                    float val = acc[rt][ct][r] + bias;
                    if (OUTH) outH[(size_t)row * HDIM + ct * 16 + lr] = (_Float16)val;
                    else      outF[(size_t)row * HDIM + ct * 16 + lr] = val;
                }
            }
        }
    }
}

// ---------------- 32-dim input gather (octant version) ----------------
__global__ __launch_bounds__(256) void gather_x_k(const int* __restrict__ row_ptr,
                                                  const int2* __restrict__ csr,
                                                  const float* __restrict__ dinv,
                                                  const float* __restrict__ X,
                                                  float* __restrict__ Y, int N) {
    int idx = blockIdx.x * 256 + threadIdx.x;
    int c = idx >> 3;
    if (c >= N) return;
    int hq = idx & 7;
    int j0 = row_ptr[c], j1 = row_ptr[c + 1];
    float di = dinv[c];
    float4 xc = *reinterpret_cast<const float4*>(X + (size_t)c * 32 + hq * 4);
    float4 acc = make_float4(di * xc.x, di * xc.y, di * xc.z, di * xc.w);
    int j = j0;
    for (; j + 3 < j1; j += 4) {
        int2 e0 = csr[j], e1 = csr[j + 1], e2 = csr[j + 2], e3 = csr[j + 3];
        float4 v0 = *reinterpret_cast<const float4*>(X + (size_t)e0.x * 32 + hq * 4);
        float4 v1 = *reinterpret_cast<const float4*>(X + (size_t)e1.x * 32 + hq * 4);
        float4 v2 = *reinterpret_cast<const float4*>(X + (size_t)e2.x * 32 + hq * 4);
        float4 v3 = *reinterpret_cast<const float4*>(X + (size_t)e3.x * 32 + hq * 4);
        float n0 = __int_as_float(e0.y), n1 = __int_as_float(e1.y);
        float n2 = __int_as_float(e2.y), n3 = __int_as_float(e3.y);
        acc.x += n0 * v0.x + n1 * v1.x + n2 * v2.x + n3 * v3.x;
        acc.y += n0 * v0.y + n1 * v1.y + n2 * v2.y + n3 * v3.y;
        acc.z += n0 * v0.z + n1 * v1.z + n2 * v2.z + n3 * v3.z;
        acc.w += n0 * v0.w + n1 * v1.w + n2 * v2.w + n3 * v3.w;
    }
    for (; j < j1; ++j) {
        int2 en = csr[j];
        float nrm = __int_as_float(en.y);
        float4 v = *reinterpret_cast<const float4*>(X + (size_t)en.x * 32 + hq * 4);
        acc.x += nrm * v.x; acc.y += nrm * v.y;
        acc.z += nrm * v.z; acc.w += nrm * v.w;
    }
    *reinterpret_cast<float4*>(Y + (size_t)c * 32 + hq * 4) = acc;
}

// ---------------- w3l = W3 @ Wlin ; consts[0] = b3.Wlin + blin ----------------
__global__ __launch_bounds__(128) void w3l_k(const float* __restrict__ W3,
                                             const float* __restrict__ b3,
                                             const float* __restrict__ Wlin,
                                             const float* __restrict__ blin,
                                             float* __restrict__ w3l,
                                             float* __restrict__ consts) {
    __shared__ float wl[128];
    __shared__ float red[128];
    int t = threadIdx.x;
    wl[t] = Wlin[t];
    __syncthreads();
    float a = 0.f;
    for (int j = 0; j < 128; ++j) a += W3[t * 128 + j] * wl[j];
    w3l[t] = a;
    red[t] = b3[t] * wl[t];
    __syncthreads();
    for (int off = 64; off > 0; off >>= 1) {
        if (t < off) red[t] += red[t + off];
        __syncthreads();
    }
    if (t == 0) consts[0] = red[0] + blin[0];
}

// ---------------- fused layer-2 gather (fp16 xw) + z projection ----------------
__global__ __launch_bounds__(256) void gather_z_k(const int* __restrict__ row_ptr,
                                                  const int2* __restrict__ csr,
                                                  const float* __restrict__ dinv,
                                                  const float* __restrict__ b,
                                                  const _Float16* __restrict__ xw,
                                                  const float* __restrict__ w3l,
                                                  float* __restrict__ z, int N) {
    int c = (blockIdx.x * 256 + threadIdx.x) >> 6;
    if (c >= N) return;
    int lane = threadIdx.x & 63;
    int half = lane >> 5;
    int hq = lane & 31;
    int j0 = row_ptr[c], j1 = row_ptr[c + 1];
    float4 acc = make_float4(0.f, 0.f, 0.f, 0.f);
    int j = j0 + half;
    for (; j + 2 < j1; j += 4) {
        int2 e0 = csr[j], e1 = csr[j + 2];
        h16x4 v0 = *reinterpret_cast<const h16x4*>(xw + (size_t)e0.x * HDIM + hq * 4);
        h16x4 v1 = *reinterpret_cast<const h16x4*>(xw + (size_t)e1.x * HDIM + hq * 4);
        float n0 = __int_as_float(e0.y), n1 = __int_as_float(e1.y);
        acc.x += n0 * (float)v0[0] + n1 * (float)v1[0];
        acc.y += n0 * (float)v0[1] + n1 * (float)v1[1];
        acc.z += n0 * (float)v0[2] + n1 * (float)v1[2];
        acc.w += n0 * (float)v0[3] + n1 * (float)v1[3];
    }
    for (; j < j1; j += 2) {
        int2 en = csr[j];
        float nrm = __int_as_float(en.y);
        h16x4 v = *reinterpret_cast<const h16x4*>(xw + (size_t)en.x * HDIM + hq * 4);
        acc.x += nrm * (float)v[0]; acc.y += nrm * (float)v[1];
        acc.z += nrm * (float)v[2]; acc.w += nrm * (float)v[3];
    }
    acc.x += __shfl_xor(acc.x, 32);
    acc.y += __shfl_xor(acc.y, 32);
    acc.z += __shfl_xor(acc.z, 32);
    acc.w += __shfl_xor(acc.w, 32);
    h16x4 xc = *reinterpret_cast<const h16x4*>(xw + (size_t)c * HDIM + hq * 4);
    float di = dinv[c];
    float4 bb = *reinterpret_cast<const float4*>(b + hq * 4);
    float4 wv = *reinterpret_cast<const float4*>(w3l + hq * 4);
    float t = fmaxf(di * (float)xc[0] + bb.x + acc.x, 0.f) * wv.x
            + fmaxf(di * (float)xc[1] + bb.y + acc.y, 0.f) * wv.y
            + fmaxf(di * (float)xc[2] + bb.z + acc.z, 0.f) * wv.z
            + fmaxf(di * (float)xc[3] + bb.w + acc.w, 0.f) * wv.w;
#pragma unroll
    for (int off = 1; off < 32; off <<= 1) t += __shfl_xor(t, off);
    if (lane == 0) z[c] = t;
}

// ---------------- scalar layer-3 gather ----------------
__global__ __launch_bounds__(256) void gather_s_k(const int* __restrict__ row_ptr,
                                                  const int2* __restrict__ csr,
                                                  const float* __restrict__ dinv,
                                                  const float* __restrict__ z,
                                                  float* __restrict__ s, int N) {
    int c = blockIdx.x * 256 + threadIdx.x;
    if (c >= N) return;
    int j0 = row_ptr[c], j1 = row_ptr[c + 1];
    float acc = dinv[c] * z[c];
    for (int j = j0; j < j1; ++j) {
        int2 en = csr[j];
        acc += __int_as_float(en.y) * z[en.x];
    }
    s[c] = acc;
}

// ---------------- graph start offsets (batch is sorted) ----------------
__global__ __launch_bounds__(256) void gstart_k(const int* __restrict__ batch,
                                                int* __restrict__ start, int N, int G) {
    int n = blockIdx.x * 256 + threadIdx.x;
    if (n > N) return;
    if (n < N) {
        int b = batch[n];
        int prev = (n == 0) ? -1 : batch[n - 1];
        for (int g = prev + 1; g <= b; ++g) start[g] = n;
    } else {
        int prev = batch[N - 1];
        for (int g = prev + 1; g <= G; ++g) start[g] = N;
    }
}

// ---------------- final: out[g] = mean_{c in g} s[c] + consts[0] ----------------
__global__ __launch_bounds__(256) void final_z_k(const float* __restrict__ s,
                                                 const int* __restrict__ start,
                                                 const float* __restrict__ consts,
                                                 const float* __restrict__ blin,
                                                 float* __restrict__ out, int G) {
    int g = blockIdx.x * 4 + (threadIdx.x >> 6);
    int lane = threadIdx.x & 63;
    if (g >= G) return;
    int a = start[g], e = start[g + 1];
    float acc = 0.f;
    for (int n = a + lane; n < e; n += 64) acc += s[n];
#pragma unroll
    for (int off = 32; off > 0; off >>= 1) acc += __shfl_down(acc, off);
    if (lane == 0) out[g] = (e > a) ? acc / (float)(e - a) + consts[0] : blin[0];
}

extern "C" void kernel_launch(void* const* d_in, const int* in_sizes, int n_in,
                              void* d_out, int out_size, void* d_ws, size_t ws_size,
                              hipStream_t stream) {
    const float* x    = (const float*)d_in[0];
    const float* W1   = (const float*)d_in[1];
    const float* b1   = (const float*)d_in[2];
    const float* W2   = (const float*)d_in[3];
    const float* b2   = (const float*)d_in[4];
    const float* W3   = (const float*)d_in[5];
    const float* b3   = (const float*)d_in[6];
    const float* Wlin = (const float*)d_in[7];
    const float* blin = (const float*)d_in[8];
    const int* ei     = (const int*)d_in[9];
    const int* batch  = (const int*)d_in[10];

    const int N = in_sizes[10];
    const int E = in_sizes[9] / 2;
    const int G = out_size;
    const size_t NH = (size_t)N * HDIM;
    const int NB = (N + 255) / 256;

    const int* row = ei;
    const int* col = ei + E;

    int2* csr      = (int2*)d_ws;                    // [E]
    float* Y       = (float*)(csr + E);              // [N,32]
    float* h1      = Y + (size_t)N * 32;             // [N,128] fp32
    _Float16* xwh  = (_Float16*)(h1 + NH);           // [N,128] fp16
    float* dis     = (float*)(xwh + NH);             // [N]
    float* dinv    = dis + N;                        // [N]
    float* zbuf    = dinv + N;                       // [N]
    float* sbuf    = zbuf + N;                       // [N]
    float* w3l     = sbuf + N;                       // [128]
    float* consts  = w3l + 128;                      // [4] (padded for 16B alignment)
    short* w1hi    = (short*)(consts + 4);           // [128*32]
    short* w1lo    = w1hi + 128 * 32;
    short* w2hi    = w1lo + 128 * 32;                // [128*128]
    short* w2lo    = w2hi + 128 * 128;
    int* deg_i     = (int*)(w2lo + 128 * 128);       // [N]
    int* row_ptr   = deg_i + N;                      // [N+1]
    int* cursor    = row_ptr + N + 1;                // [N]
    int* gstart    = cursor + N;                     // [G+1]
    int* incl      = gstart + G + 1;                 // [N]
    int* partial   = incl + N;                       // [NB]

    float* outf = (float*)d_out;

    // ---- CSR build + weight prep ----
    hipMemsetAsync(deg_i, 0, (size_t)N * sizeof(int), stream);
    hipMemsetAsync(cursor, 0, (size_t)N * sizeof(int), stream);
    deg_hist_k<<<(E + 255) / 256, 256, 0, stream>>>(col, deg_i, E);
    scan1_k<<<NB, 256, 0, stream>>>(deg_i, incl, partial, dis, dinv, N);
    scan2_k<<<1, 512, 0, stream>>>(partial, NB);
    scan3_k<<<NB, 256, 0, stream>>>(deg_i, incl, partial, row_ptr, N);
    csr_fill_k<<<(E + 255) / 256, 256, 0, stream>>>(row, col, dis, row_ptr, cursor, csr, E);
    gstart_k<<<(N + 256) / 256, 256, 0, stream>>>(batch, gstart, N, G);
    wsplit_k<<<(32 * 128 + 255) / 256, 256, 0, stream>>>(W1, w1hi, w1lo, 32);
    wsplit_k<<<(128 * 128 + 255) / 256, 256, 0, stream>>>(W2, w2hi, w2lo, 128);
    w3l_k<<<1, 128, 0, stream>>>(W3, b3, Wlin, blin, w3l, consts);

    const int mfma_grid = (N + 127) / 128;
    const int wave_grid = (N + 3) / 4;

    // layer 1 (aggregate-first): Y = A_hat X ; h1 = Y W1 + b1 (fp32)
    gather_x_k<<<(N * 8 + 255) / 256, 256, 0, stream>>>(row_ptr, csr, dinv, x, Y, N);
    gemm_mfma2<32, false, true, false><<<mfma_grid, 256, 0, stream>>>(Y, w1hi, w1lo, b1, h1, nullptr, N);
    // layer 2: xwh = relu(h1) W2 (fp16 out) ; fused gather(+b2) + z = relu(h2).w3l
    gemm_mfma2<128, true, false, true><<<mfma_grid, 256, 0, stream>>>(h1, w2hi, w2lo, nullptr, nullptr, xwh, N);
    gather_z_k<<<wave_grid, 256, 0, stream>>>(row_ptr, csr, dinv, b2, xwh, w3l, zbuf, N);
    // layer 3 (collapsed): s = dinv*z + A-gather(z)
    gather_s_k<<<(N + 255) / 256, 256, 0, stream>>>(row_ptr, csr, dinv, zbuf, sbuf, N);
    // final: segment mean + consts
    final_z_k<<<(G + 3) / 4, 256, 0, stream>>>(sbuf, gstart, consts, blin, outf, G);
}